// Round 8
// baseline (300.257 us; speedup 1.0000x reference)
//
#include <hip/hip_runtime.h>
#include <hip/hip_bf16.h>

typedef __attribute__((ext_vector_type(8))) short short8;
typedef __attribute__((ext_vector_type(4))) short short4v;
typedef __attribute__((ext_vector_type(4))) float float4v;

static __device__ __forceinline__ unsigned short f2bf(float f) {
    unsigned u = __float_as_uint(f);
    unsigned r = (u + 0x7FFF + ((u >> 16) & 1)) >> 16;  // RNE
    return (unsigned short)r;
}

// ---------------------------------------------------------------------------
// ONE prep kernel (unchanged from R7 — known good).
//  [0,8)     : K1b[half][co][k32] bf16 (DCLS gather, conv1 B-operand layout)
//  [8,208)   : Kt[kk][co][ci] bf16 (DCLS gather, conv2 B-operand layout)
//  [208,404) : fc1w fp32 -> w1b bf16 (native (128,3136) layout)
// ---------------------------------------------------------------------------
__global__ __launch_bounds__(256) void prep_all(
    const float* __restrict__ w1, const float* __restrict__ p1,
    const float* __restrict__ w2, const float* __restrict__ p2,
    const float* __restrict__ fc1w,
    unsigned short* __restrict__ K1b,   // (2,32,32)
    unsigned short* __restrict__ Kt,    // (25,64,32)
    unsigned short* __restrict__ w1b) { // (128,3136)
    const int blk = blockIdx.x;
    const int t = threadIdx.x;

    if (blk < 8) {
        int cell = blk * 256 + t;          // 0..2047
        int half = cell >> 10;
        int co = (cell >> 5) & 31;
        int k = cell & 31;
        int ky = (k >> 3) + 4 * half;
        int kx = k & 7;
        float acc = 0.f;
        if (kx < 5 && ky < 5) {
#pragma unroll 8
            for (int kc = 0; kc < 16; ++kc) {
                float wv = w1[co * 16 + kc];
                float pa = p1[co * 16 + kc];
                float pb = p1[512 + co * 16 + kc];
                float pos1 = fminf(fmaxf(pa, -2.f), 2.f) + 2.f;
                float pos2 = fminf(fmaxf(pb, -2.f), 2.f) + 2.f;
                int i1 = (int)floorf(pos1);
                int i2 = (int)floorf(pos2);
                float r1 = pos1 - (float)i1;
                float r2 = pos2 - (float)i2;
                float c = 0.f;
                if (i1 == ky && i2 == kx) c += (1.f - r1) * (1.f - r2);
                if (i1 + 1 == ky && i2 == kx) c += r1 * (1.f - r2);
                if (i1 == ky && i2 + 1 == kx) c += (1.f - r1) * r2;
                if (i1 + 1 == ky && i2 + 1 == kx) c += r1 * r2;
                acc += wv * c;
            }
        }
        K1b[cell] = f2bf(acc);
    } else if (blk < 208) {
        int cell = (blk - 8) * 256 + t;    // 0..51199
        int kk = cell >> 11;
        int co = (cell >> 5) & 63;
        int ci = cell & 31;
        int ky = kk / 5;
        int kx = kk - 5 * ky;
        const int base = (co * 32 + ci) * 32;
        float acc = 0.f;
#pragma unroll 8
        for (int kc = 0; kc < 32; ++kc) {
            float wv = w2[base + kc];
            float pa = p2[base + kc];
            float pb = p2[65536 + base + kc];
            float pos1 = fminf(fmaxf(pa, -2.f), 2.f) + 2.f;
            float pos2 = fminf(fmaxf(pb, -2.f), 2.f) + 2.f;
            int i1 = (int)floorf(pos1);
            int i2 = (int)floorf(pos2);
            float r1 = pos1 - (float)i1;
            float r2 = pos2 - (float)i2;
            float c = 0.f;
            if (i1 == ky && i2 == kx) c += (1.f - r1) * (1.f - r2);
            if (i1 + 1 == ky && i2 == kx) c += r1 * (1.f - r2);
            if (i1 == ky && i2 + 1 == kx) c += (1.f - r1) * r2;
            if (i1 + 1 == ky && i2 + 1 == kx) c += r1 * r2;
            acc += wv * c;
        }
        Kt[cell] = f2bf(acc);
    } else {
        int i8 = ((blk - 208) * 256 + t) * 8;  // < 401408 exactly (196 blocks)
        float4 v0 = *(const float4*)(fc1w + i8);
        float4 v1 = *(const float4*)(fc1w + i8 + 4);
        short8 o = {(short)f2bf(v0.x), (short)f2bf(v0.y), (short)f2bf(v0.z),
                    (short)f2bf(v0.w), (short)f2bf(v1.x), (short)f2bf(v1.y),
                    (short)f2bf(v1.z), (short)f2bf(v1.w)};
        *(short8*)(w1b + i8) = o;
    }
}

// ---------------------------------------------------------------------------
// Fused conv, both on MFMA, positions on the A-side (pool = 3 in-lane fmax).
// conv1: 7x7 tiles of 4x4 px, K=64 taps = 2 MFMAs x 2 co-tiles (unchanged).
// conv2: 14 strip-tiles (7 ty x 2 sx) of 2x8 px — exactly covers pooled 7x7:
//        1400 MFMA/block (was 1600), 350 A-reads (was 400), pY always valid.
// LDS 31680 B (h1p[18][18][36] + sm4[4][29][36], sm_xb aliased into h1p)
//   -> 5 blocks/CU if AGPR pool is separate from VGPR (A/B experiment).
// ---------------------------------------------------------------------------
__global__ __launch_bounds__(256, 4) void fused_conv_mfma(
    const float* __restrict__ x,             // (B,1,28,28) fp32
    const unsigned short* __restrict__ K1b,  // (2,32,32)
    const unsigned short* __restrict__ Kt,   // (25,64,32)
    const float* __restrict__ b1,
    const float* __restrict__ b2,
    unsigned short* __restrict__ h2) {       // (B,3136) bf16
    __shared__ __align__(16) unsigned short h1p[18 * 18 * 36];  // 23328 B
    __shared__ __align__(16) unsigned short sm4[4 * 29 * 36];   // 8352 B

    const int b = blockIdx.x;
    const int tid = threadIdx.x;
    const int lane = tid & 63;
    const int wv = tid >> 6;
    const int n16 = lane & 15;
    const int cig = lane >> 4;

    // conv1 A-side m-mapping (4x4 tile): quad + in-quad
    const int yi = 2 * (n16 >> 3) + ((n16 >> 1) & 1);  // 0..3
    const int xi = 2 * ((n16 >> 2) & 1) + (n16 & 1);   // 0..3
    const int pYo = cig >> 1, pXo = cig & 1;           // conv1 D pooled offsets

    unsigned short* sm_xb = h1p;  // alias: first 784 shorts (zeroed later)

    // phase0: stage image bf16 + start weight-frag loads (global, independent)
    {
        const float* xb = x + (size_t)b * 784;
        for (int t = tid; t < 784; t += 256) sm_xb[t] = f2bf(xb[t]);
    }
    short8 bw[2][2];
    float bias1[2], bias2[4];
#pragma unroll
    for (int cot = 0; cot < 2; ++cot) {
#pragma unroll
        for (int h = 0; h < 2; ++h)
            bw[cot][h] = *(const short8*)(K1b + (h * 32 + cot * 16 + n16) * 32 + cig * 8);
        bias1[cot] = b1[cot * 16 + n16];
    }
#pragma unroll
    for (int cot = 0; cot < 4; ++cot) bias2[cot] = b2[cot * 16 + n16];
    __syncthreads();

    // phase1: build 4 shifted copies (width 36; copy s pos p = col p+s-4; row 28 zero)
    //         while threads >=120 zero h1p beyond the sm_xb alias region
    if (tid < 116) {
        int s = tid / 29;
        int r = tid - s * 29;
        unsigned short* dst = sm4 + (s * 29 + r) * 36;
        bool rok = r < 28;
#pragma unroll
        for (int g = 0; g < 9; ++g) {
            short4v v;
#pragma unroll
            for (int e = 0; e < 4; ++e) {
                int c = g * 4 + e + s - 4;
                v[e] = (short)((rok && (unsigned)c < 28u) ? sm_xb[r * 28 + c]
                                                          : (unsigned short)0);
            }
            *(short4v*)(dst + g * 4) = v;
        }
    } else if (tid >= 120) {
        for (int i = 98 + (tid - 120); i < 1458; i += 136)
            ((uint4*)h1p)[i] = uint4{0, 0, 0, 0};
    }
    __syncthreads();
    // phase2: zero the aliased region (first 98 uint4 = 1568 B)
    if (tid < 98) ((uint4*)h1p)[tid] = uint4{0, 0, 0, 0};
    __syncthreads();

    // conv1: 49 tiles (7x7 of 4x4 px), wave-split; 4 MFMA + 2 stores per tile
    {
        const int s1 = (xi + 2) & 3;
        const int pb1 = (xi + 2) & ~3;
        const unsigned short* a1base = sm4 + s1 * (29 * 36) + pb1;
        for (int i = 0; i < 13; ++i) {
            int t = wv + 4 * i;
            if (t < 49) {
                int tY = t / 7, tX = t - 7 * tY;
                const unsigned short* ab = a1base + 4 * tX;
                int r0 = 4 * tY + yi - 2 + cig;           // window rows 0..3
                int r1 = r0 + 4;                          // window rows 4..7
                int rr0 = ((unsigned)r0 < 28u) ? r0 : 28; // 28 = zero row
                int rr1 = ((unsigned)r1 < 28u) ? r1 : 28;
                short4v lo0 = *(const short4v*)(ab + rr0 * 36);
                short4v hi0 = *(const short4v*)(ab + rr0 * 36 + 4);
                short4v lo1 = *(const short4v*)(ab + rr1 * 36);
                short4v hi1 = *(const short4v*)(ab + rr1 * 36 + 4);
                short8 af0 = {lo0[0], lo0[1], lo0[2], lo0[3], hi0[0], hi0[1], hi0[2], hi0[3]};
                short8 af1 = {lo1[0], lo1[1], lo1[2], lo1[3], hi1[0], hi1[1], hi1[2], hi1[3]};
                int pY = 2 * tY + pYo, pX = 2 * tX + pXo;
#pragma unroll
                for (int cot = 0; cot < 2; ++cot) {
                    float4v acc = {0.f, 0.f, 0.f, 0.f};
                    acc = __builtin_amdgcn_mfma_f32_16x16x32_bf16(af0, bw[cot][0], acc, 0, 0, 0);
                    acc = __builtin_amdgcn_mfma_f32_16x16x32_bf16(af1, bw[cot][1], acc, 0, 0, 0);
                    float v = fmaxf(fmaxf(acc[0], acc[1]), fmaxf(acc[2], acc[3]));
                    v = fmaxf(v + bias1[cot], 0.f);
                    h1p[((pY + 2) * 18 + (pX + 2)) * 36 + cot * 16 + n16] = f2bf(v);
                }
            }
        }
    }
    __syncthreads();

    // conv2: 14 strip-tiles (ty = t>>1, sx = t&1), strip = 2 rows x 8 cols.
    // A-side m: qx = m>>2, dy = (m>>1)&1, dx = m&1 -> y = 2ty+dy, x = 8sx+2qx+dx.
    // D rows per lane = quad (lane>>4) -> pool over 4 regs; pX = 4sx + (lane>>4).
    {
        const int qx = n16 >> 2, dy = (n16 >> 1) & 1, dxx = n16 & 1;
        const unsigned short* Ab[4];
        int tyA[4], pXb[4];
        bool valid[4];
#pragma unroll
        for (int i = 0; i < 4; ++i) {
            int t = wv + 4 * i;
            valid[i] = t < 14;
            int ts = valid[i] ? t : 0;
            int ty = ts >> 1, sx = ts & 1;
            int y = 2 * ty + dy;                 // 0..13
            int xc = 8 * sx + 2 * qx + dxx;      // 0..15
            if (xc > 13) xc = 13;                // phantom lanes (discarded below)
            Ab[i] = h1p + (y * 18 + xc) * 36 + cig * 8;
            tyA[i] = ty;
            pXb[i] = 4 * sx;
        }

        float4v acc[4][4];  // [tile][cot] = 64 AGPR
#pragma unroll
        for (int i = 0; i < 4; ++i)
#pragma unroll
            for (int c = 0; c < 4; ++c) acc[i][c] = float4v{0.f, 0.f, 0.f, 0.f};

#pragma unroll
        for (int ky = 0; ky < 5; ++ky) {
#pragma unroll
            for (int kx = 0; kx < 5; ++kx) {
                int kk = ky * 5 + kx;
                short8 wf[4];
#pragma unroll
                for (int cot = 0; cot < 4; ++cot)
                    wf[cot] = *(const short8*)(Kt + ((kk * 64 + cot * 16 + n16) * 32 + cig * 8));
#pragma unroll
                for (int i = 0; i < 4; ++i) {
                    if (valid[i]) {
                        short8 af = *(const short8*)(Ab[i] + (ky * 18 + kx) * 36);
#pragma unroll
                        for (int cot = 0; cot < 4; ++cot)
                            acc[i][cot] = __builtin_amdgcn_mfma_f32_16x16x32_bf16(
                                af, wf[cot], acc[i][cot], 0, 0, 0);
                    }
                }
            }
        }

        unsigned short* outb = h2 + (size_t)b * 3136;
#pragma unroll
        for (int i = 0; i < 4; ++i) {
            if (valid[i]) {
                int pX = pXb[i] + cig;           // 0..7; 7 = phantom
                bool ok = pX < 7;
#pragma unroll
                for (int cot = 0; cot < 4; ++cot) {
                    float4v a = acc[i][cot];
                    float v = fmaxf(fmaxf(a[0], a[1]), fmaxf(a[2], a[3]));
                    v = fmaxf(v + bias2[cot], 0.f);
                    if (ok)
                        outb[(cot * 16 + n16) * 49 + tyA[i] * 7 + pX] = f2bf(v);
                }
            }
        }
    }
}

// ---------------------------------------------------------------------------
// FC1 MFMA, 64-row blocks: partials[kh](B,128) = A @ W^T slice kh (K-split 7).
// A-tile staged in LDS (shared by all waves); waves split N (2 n-tiles each)
// -> W-fragment gathers cut 4x vs 16-row blocks. Plain stores, no atomics.
__global__ __launch_bounds__(256) void fc1_mfma(
    const unsigned short* __restrict__ A,
    const unsigned short* __restrict__ Wb,
    float* __restrict__ part, size_t PB) {  // PB = B*128
    __shared__ __align__(16) unsigned short As[64 * 72];  // stride 72 breaks banks
    const int blk = blockIdx.x;
    const int kh = blk % 7;
    const int m0 = (blk / 7) * 64;
    const int tid = threadIdx.x;
    const int wv = tid >> 6;
    const int lane = tid & 63;
    const int n16 = lane & 15;
    const int cig = lane >> 4;

    float4v acc[4][2];  // [mt][j]
#pragma unroll
    for (int mt = 0; mt < 4; ++mt)
#pragma unroll
        for (int j = 0; j < 2; ++j) acc[mt][j] = float4v{0.f, 0.f, 0.f, 0.f};

    for (int it = 0; it < 7; ++it) {
        int k0 = kh * 448 + it * 64;
        __syncthreads();
#pragma unroll
        for (int i = 0; i < 2; ++i) {
            int p = tid + 256 * i;         // 0..511 = 64 rows x 8 k-octs
            int r = p >> 3, ko = (p & 7) * 8;
            *(short8*)(As + r * 72 + ko) =
                *(const short8*)(A + (size_t)(m0 + r) * 3136 + k0 + ko);
        }
        __syncthreads();
#pragma unroll
        for (int h = 0; h < 2; ++h) {
            short8 af[4];
#pragma unroll
            for (int mt = 0; mt < 4; ++mt)
                af[mt] = *(const short8*)(As + (mt * 16 + n16) * 72 + h * 32 + cig * 8);
            short8 wf[2];
#pragma unroll
            for (int j = 0; j < 2; ++j)
                wf[j] = *(const short8*)(Wb + (size_t)((wv * 2 + j) * 16 + n16) * 3136 +
                                         k0 + h * 32 + cig * 8);
#pragma unroll
            for (int mt = 0; mt < 4; ++mt)
#pragma unroll
                for (int j = 0; j < 2; ++j)
                    acc[mt][j] = __builtin_amdgcn_mfma_f32_16x16x32_bf16(
                        af[mt], wf[j], acc[mt][j], 0, 0, 0);
        }
    }
    float* o = part + (size_t)kh * PB;
#pragma unroll
    for (int mt = 0; mt < 4; ++mt)
#pragma unroll
        for (int j = 0; j < 2; ++j)
#pragma unroll
            for (int r = 0; r < 4; ++r) {
                int row = m0 + mt * 16 + cig * 4 + r;
                o[(size_t)row * 128 + (wv * 2 + j) * 16 + n16] = acc[mt][j][r];
            }
}

// FC2, k-split 4: thread (b,n,q) covers k [32q,32q+32); shfl-xor pair reduce.
// out(B,10) = relu(sum of 7 fc1 partials + fc1b) @ W(10,128)^T + b2
__global__ __launch_bounds__(256) void fc2_kernel(
    const float* __restrict__ part, size_t PB,
    const float* __restrict__ fc1b,
    const float* __restrict__ W, const float* __restrict__ bias,
    float* __restrict__ out, int total4) {
    __shared__ float smW[10 * 132];
    __shared__ float smB1[128];
    __shared__ float smB[10];
    int t = threadIdx.x;
    for (int i = t; i < 1280; i += 256) {
        int n = i >> 7, k = i & 127;
        smW[n * 132 + k] = W[i];
    }
    if (t < 128) smB1[t] = fc1b[t];
    if (t < 10) smB[t] = bias[t];
    __syncthreads();
    int idx = blockIdx.x * 256 + t;
    if (idx < total4) {
        int j = idx >> 2;         // (b,n)
        int q = idx & 3;          // k-quarter
        int b = j / 10;
        int n = j - b * 10;
        const float* pb = part + (size_t)b * 128 + q * 32;
        const float4* bb = (const float4*)(smB1 + q * 32);
        const float4* wr = (const float4*)(smW + n * 132 + q * 32);
        float acc = 0.f;
#pragma unroll
        for (int c = 0; c < 8; ++c) {
            float4 s = *(const float4*)(pb + 4 * c);
#pragma unroll
            for (int jj = 1; jj < 7; ++jj) {
                float4 pj = *(const float4*)(pb + (size_t)jj * PB + 4 * c);
                s.x += pj.x; s.y += pj.y; s.z += pj.z; s.w += pj.w;
            }
            float4 bv = bb[c];
            float4 w = wr[c];
            acc += fmaxf(s.x + bv.x, 0.f) * w.x + fmaxf(s.y + bv.y, 0.f) * w.y +
                   fmaxf(s.z + bv.z, 0.f) * w.z + fmaxf(s.w + bv.w, 0.f) * w.w;
        }
        acc += __shfl_xor(acc, 1);
        acc += __shfl_xor(acc, 2);
        if (q == 0) out[j] = acc + smB[n];
    }
}

extern "C" void kernel_launch(void* const* d_in, const int* in_sizes, int n_in,
                              void* d_out, int out_size, void* d_ws, size_t ws_size,
                              hipStream_t stream) {
    const float* x    = (const float*)d_in[0];
    const float* w1   = (const float*)d_in[1];
    const float* p1   = (const float*)d_in[2];
    const float* b1   = (const float*)d_in[3];
    const float* w2   = (const float*)d_in[4];
    const float* p2   = (const float*)d_in[5];
    const float* b2   = (const float*)d_in[6];
    const float* fc1w = (const float*)d_in[7];
    const float* fc1b = (const float*)d_in[8];
    const float* fc2w = (const float*)d_in[9];
    const float* fc2b = (const float*)d_in[10];
    float* out = (float*)d_out;

    const int B = in_sizes[0] / 784;  // 4096

    float* ws = (float*)d_ws;
    unsigned short* Kt  = (unsigned short*)ws;             // 51200 sh = 25600 f
    unsigned short* K1b = (unsigned short*)(ws + 25600);   // 2048 sh = 1024 f
    unsigned short* w1b = (unsigned short*)(ws + 26624);   // 401408 sh = 200704 f
    unsigned short* h2b = (unsigned short*)(ws + 227328);  // B*3136 sh = B*1568 f
    float* fc1p = ws + 227328 + (size_t)B * 1568;          // 7*B*128 f

    prep_all<<<404, 256, 0, stream>>>(w1, p1, w2, p2, fc1w, K1b, Kt, w1b);
    fused_conv_mfma<<<B, 256, 0, stream>>>(x, K1b, Kt, b1, b2, h2b);
    fc1_mfma<<<(B / 64) * 7, 256, 0, stream>>>(h2b, w1b, fc1p, (size_t)B * 128);
    fc2_kernel<<<(B * 10 * 4 + 255) / 256, 256, 0, stream>>>(
        fc1p, (size_t)B * 128, fc1b, fc2w, fc2b, out, B * 10 * 4);
}

// Round 9
// 243.436 us; speedup vs baseline: 1.2334x; 1.2334x over previous
//
#include <hip/hip_runtime.h>
#include <hip/hip_bf16.h>

typedef __attribute__((ext_vector_type(8))) short short8;
typedef __attribute__((ext_vector_type(4))) short short4v;
typedef __attribute__((ext_vector_type(4))) float float4v;

static __device__ __forceinline__ unsigned short f2bf(float f) {
    unsigned u = __float_as_uint(f);
    unsigned r = (u + 0x7FFF + ((u >> 16) & 1)) >> 16;  // RNE
    return (unsigned short)r;
}

// ---------------------------------------------------------------------------
// ONE prep kernel (R7 version — known good with the R7 fused kernel).
//  [0,8)     : K1b[co][k64] bf16 (DCLS gather, conv1 B-operand layout)
//  [8,208)   : Kt[kk][co][ci] bf16 (DCLS gather, conv2 B-operand layout)
//  [208,404) : fc1w fp32 -> w1b bf16 (native (128,3136) layout)
// ---------------------------------------------------------------------------
__global__ __launch_bounds__(256) void prep_all(
    const float* __restrict__ w1, const float* __restrict__ p1,
    const float* __restrict__ w2, const float* __restrict__ p2,
    const float* __restrict__ fc1w,
    unsigned short* __restrict__ K1b,   // (32,64)
    unsigned short* __restrict__ Kt,    // (25,64,32)
    unsigned short* __restrict__ w1b) { // (128,3136)
    const int blk = blockIdx.x;
    const int t = threadIdx.x;

    if (blk < 8) {
        // conv1 weights, B-layout: K1b[co][k], k = wr*8 + kx (zero-padded taps)
        int cell = blk * 256 + t;          // 0..2047
        int co = cell >> 6;
        int k = cell & 63;
        int wr = k >> 3;
        int kx = k & 7;
        float acc = 0.f;
        if (wr < 5 && kx < 5) {
#pragma unroll 8
            for (int kc = 0; kc < 16; ++kc) {
                float wv = w1[co * 16 + kc];
                float pa = p1[co * 16 + kc];
                float pb = p1[512 + co * 16 + kc];
                float pos1 = fminf(fmaxf(pa, -2.f), 2.f) + 2.f;
                float pos2 = fminf(fmaxf(pb, -2.f), 2.f) + 2.f;
                int i1 = (int)floorf(pos1);
                int i2 = (int)floorf(pos2);
                float r1 = pos1 - (float)i1;
                float r2 = pos2 - (float)i2;
                float c = 0.f;
                if (i1 == wr && i2 == kx) c += (1.f - r1) * (1.f - r2);
                if (i1 + 1 == wr && i2 == kx) c += r1 * (1.f - r2);
                if (i1 == wr && i2 + 1 == kx) c += (1.f - r1) * r2;
                if (i1 + 1 == wr && i2 + 1 == kx) c += r1 * r2;
                acc += wv * c;
            }
        }
        K1b[cell] = f2bf(acc);
    } else if (blk < 208) {
        int cell = (blk - 8) * 256 + t;    // 0..51199
        int kk = cell >> 11;
        int co = (cell >> 5) & 63;
        int ci = cell & 31;
        int ky = kk / 5;
        int kx = kk - 5 * ky;
        const int base = (co * 32 + ci) * 32;
        float acc = 0.f;
#pragma unroll 8
        for (int kc = 0; kc < 32; ++kc) {
            float wv = w2[base + kc];
            float pa = p2[base + kc];
            float pb = p2[65536 + base + kc];
            float pos1 = fminf(fmaxf(pa, -2.f), 2.f) + 2.f;
            float pos2 = fminf(fmaxf(pb, -2.f), 2.f) + 2.f;
            int i1 = (int)floorf(pos1);
            int i2 = (int)floorf(pos2);
            float r1 = pos1 - (float)i1;
            float r2 = pos2 - (float)i2;
            float c = 0.f;
            if (i1 == ky && i2 == kx) c += (1.f - r1) * (1.f - r2);
            if (i1 + 1 == ky && i2 == kx) c += r1 * (1.f - r2);
            if (i1 == ky && i2 + 1 == kx) c += (1.f - r1) * r2;
            if (i1 + 1 == ky && i2 + 1 == kx) c += r1 * r2;
            acc += wv * c;
        }
        Kt[cell] = f2bf(acc);
    } else {
        int i8 = ((blk - 208) * 256 + t) * 8;  // < 401408 exactly (196 blocks)
        float4 v0 = *(const float4*)(fc1w + i8);
        float4 v1 = *(const float4*)(fc1w + i8 + 4);
        short8 o = {(short)f2bf(v0.x), (short)f2bf(v0.y), (short)f2bf(v0.z),
                    (short)f2bf(v0.w), (short)f2bf(v1.x), (short)f2bf(v1.y),
                    (short)f2bf(v1.z), (short)f2bf(v1.w)};
        *(short8*)(w1b + i8) = o;
    }
}

// ---------------------------------------------------------------------------
// Fused conv (R7 version — measured 153 us). Both convs on MFMA, positions on
// the A-side (pool = 3 in-lane fmax, every lane emits one pooled output).
// conv1: 7x7 tiles of 4x4 px, K=64 taps = 2 MFMAs x 2 co-tiles, weights in
//        registers; image rows via 4 phase-shifted LDS copies (2x ds_read_b64).
// conv2: 16 uniform tiles of 4x4 px (straight-line 25-tap loop, stride-40
//        ci rows -> aligned ds_read_b128, bank-spread period 8).
// One block (4 waves) per image; LDS 40.5 KB -> 4 blocks/CU.
// ---------------------------------------------------------------------------
__global__ __launch_bounds__(256, 4) void fused_conv_mfma(
    const float* __restrict__ x,             // (B,1,28,28) fp32
    const unsigned short* __restrict__ K1b,  // (32,64)
    const unsigned short* __restrict__ Kt,   // (25,64,32)
    const float* __restrict__ b1,
    const float* __restrict__ b2,
    unsigned short* __restrict__ h2) {       // (B,3136) bf16
    __shared__ __align__(16) unsigned short h1p[18 * 20 * 40];  // [yy][xx][ci(+pad)]
    __shared__ __align__(16) unsigned short sm4[4 * 29 * 44];   // 4 shifted copies; row 28 zero
    __shared__ __align__(16) unsigned short sm_xb[784];

    const int b = blockIdx.x;
    const int tid = threadIdx.x;
    const int lane = tid & 63;
    const int wv = tid >> 6;
    const int n16 = lane & 15;
    const int cig = lane >> 4;

    // input-position offsets (A-side m = n16): quad + in-quad
    const int yi = 2 * (n16 >> 3) + ((n16 >> 1) & 1);  // 0..3
    const int xi = 2 * ((n16 >> 2) & 1) + (n16 & 1);   // 0..3
    // output pooled offsets (D rows: quad = cig)
    const int pYo = cig >> 1, pXo = cig & 1;

    // 1) zero h1p (borders + ci-pads must be 0) + stage image as bf16
    for (int t = tid; t < 1800; t += 256) ((uint4*)h1p)[t] = uint4{0, 0, 0, 0};
    {
        const float* xb = x + (size_t)b * 784;
        for (int t = tid; t < 784; t += 256) sm_xb[t] = f2bf(xb[t]);
    }
    __syncthreads();

    // 2) build 4 shifted copies (copy s pos p = pixel col p+s-4; row 28 = zeros)
    if (tid < 116) {
        int s = tid / 29;
        int r = tid - s * 29;
        unsigned short* dst = sm4 + (s * 29 + r) * 44;
        bool rok = r < 28;
#pragma unroll
        for (int g = 0; g < 11; ++g) {
            short4v v;
#pragma unroll
            for (int e = 0; e < 4; ++e) {
                int c = g * 4 + e + s - 4;
                v[e] = (short)((rok && (unsigned)c < 28u) ? sm_xb[r * 28 + c]
                                                          : (unsigned short)0);
            }
            *(short4v*)(dst + g * 4) = v;
        }
    }

    // conv1 weight B-frags (register-resident) + biases
    short8 bw[2][2];
    float bias1[2], bias2[4];
#pragma unroll
    for (int cot = 0; cot < 2; ++cot) {
#pragma unroll
        for (int h = 0; h < 2; ++h)
            bw[cot][h] = *(const short8*)(K1b + (cot * 16 + n16) * 64 + h * 32 + cig * 8);
        bias1[cot] = b1[cot * 16 + n16];
    }
#pragma unroll
    for (int cot = 0; cot < 4; ++cot) bias2[cot] = b2[cot * 16 + n16];

    // per-lane constant part of sm4 address (4tX is always 0 mod 4)
    const int s1 = (xi + 2) & 3;
    const int pb1 = (xi + 2) & ~3;
    const unsigned short* a1base = sm4 + s1 * (29 * 44) + pb1;

    __syncthreads();

    // 3) conv1: 49 tiles (7x7 of 4x4 px), wave-split; 4 MFMA + 2 stores/tile
    for (int i = 0; i < 13; ++i) {
        int t = wv + 4 * i;
        if (t < 49) {
            int tY = t / 7, tX = t - 7 * tY;
            const unsigned short* ab = a1base + 4 * tX;
            int r0 = 4 * tY + yi - 2 + cig;           // window rows 0..3
            int r1 = r0 + 4;                          // window rows 4..7
            int rr0 = ((unsigned)r0 < 28u) ? r0 : 28; // 28 = zero row
            int rr1 = ((unsigned)r1 < 28u) ? r1 : 28;
            short4v lo0 = *(const short4v*)(ab + rr0 * 44);
            short4v hi0 = *(const short4v*)(ab + rr0 * 44 + 4);
            short4v lo1 = *(const short4v*)(ab + rr1 * 44);
            short4v hi1 = *(const short4v*)(ab + rr1 * 44 + 4);
            short8 af0 = {lo0[0], lo0[1], lo0[2], lo0[3], hi0[0], hi0[1], hi0[2], hi0[3]};
            short8 af1 = {lo1[0], lo1[1], lo1[2], lo1[3], hi1[0], hi1[1], hi1[2], hi1[3]};
            int pY = 2 * tY + pYo, pX = 2 * tX + pXo;
#pragma unroll
            for (int cot = 0; cot < 2; ++cot) {
                float4v acc = {0.f, 0.f, 0.f, 0.f};
                acc = __builtin_amdgcn_mfma_f32_16x16x32_bf16(af0, bw[cot][0], acc, 0, 0, 0);
                acc = __builtin_amdgcn_mfma_f32_16x16x32_bf16(af1, bw[cot][1], acc, 0, 0, 0);
                float v = fmaxf(fmaxf(acc[0], acc[1]), fmaxf(acc[2], acc[3]));
                v = fmaxf(v + bias1[cot], 0.f);
                h1p[((pY + 2) * 20 + (pX + 2)) * 40 + cot * 16 + n16] = f2bf(v);
            }
        }
    }
    __syncthreads();

    // 4) conv2: wave owns 4 tiles (16 tiles of 4x4 px over pooled 8x8)
    const unsigned short* Ab[4];
    int pY2[4], pX2[4];
#pragma unroll
    for (int i = 0; i < 4; ++i) {
        int t = wv * 4 + i;
        int tY = t >> 2, tX = t & 3;
        int y2 = 4 * tY + yi;
        y2 = (y2 > 13) ? 13 : y2;   // phantom rows clamped (results discarded)
        int x2 = 4 * tX + xi;       // <=15, +kx fits cols 20
        Ab[i] = h1p + (y2 * 20 + x2) * 40 + cig * 8;
        pY2[i] = 2 * tY + pYo;
        pX2[i] = 2 * tX + pXo;
    }

    float4v acc[4][4];  // [tile][cot] = 64 AGPR
#pragma unroll
    for (int i = 0; i < 4; ++i)
#pragma unroll
        for (int c = 0; c < 4; ++c) acc[i][c] = float4v{0.f, 0.f, 0.f, 0.f};

#pragma unroll
    for (int ky = 0; ky < 5; ++ky) {
#pragma unroll
        for (int kx = 0; kx < 5; ++kx) {
            int kk = ky * 5 + kx;
            short8 wf[4];
#pragma unroll
            for (int cot = 0; cot < 4; ++cot)
                wf[cot] = *(const short8*)(Kt + ((kk * 64 + cot * 16 + n16) * 32 + cig * 8));
#pragma unroll
            for (int i = 0; i < 4; ++i) {
                short8 af = *(const short8*)(Ab[i] + (ky * 20 + kx) * 40);
#pragma unroll
                for (int cot = 0; cot < 4; ++cot)
                    acc[i][cot] = __builtin_amdgcn_mfma_f32_16x16x32_bf16(
                        af, wf[cot], acc[i][cot], 0, 0, 0);
            }
        }
    }

    unsigned short* outb = h2 + (size_t)b * 3136;
#pragma unroll
    for (int i = 0; i < 4; ++i) {
        bool ok = (pY2[i] < 7) & (pX2[i] < 7);
#pragma unroll
        for (int cot = 0; cot < 4; ++cot) {
            float4v a = acc[i][cot];
            float v = fmaxf(fmaxf(a[0], a[1]), fmaxf(a[2], a[3]));
            v = fmaxf(v + bias2[cot], 0.f);
            if (ok)
                outb[(cot * 16 + n16) * 49 + pY2[i] * 7 + pX2[i]] = f2bf(v);
        }
    }
}

// ---------------------------------------------------------------------------
// FC1 MFMA, 64-row blocks (R8 version): partials[kh](B,128) = A @ W^T slice kh
// (K-split 7). A-tile staged in LDS (shared by all waves); waves split N
// -> W-fragment gathers cut 4x vs 16-row blocks. Plain stores, no atomics.
__global__ __launch_bounds__(256) void fc1_mfma(
    const unsigned short* __restrict__ A,
    const unsigned short* __restrict__ Wb,
    float* __restrict__ part, size_t PB) {  // PB = B*128
    __shared__ __align__(16) unsigned short As[64 * 72];  // stride 72 breaks banks
    const int blk = blockIdx.x;
    const int kh = blk % 7;
    const int m0 = (blk / 7) * 64;
    const int tid = threadIdx.x;
    const int wv = tid >> 6;
    const int lane = tid & 63;
    const int n16 = lane & 15;
    const int cig = lane >> 4;

    float4v acc[4][2];  // [mt][j]
#pragma unroll
    for (int mt = 0; mt < 4; ++mt)
#pragma unroll
        for (int j = 0; j < 2; ++j) acc[mt][j] = float4v{0.f, 0.f, 0.f, 0.f};

    for (int it = 0; it < 7; ++it) {
        int k0 = kh * 448 + it * 64;
        __syncthreads();
#pragma unroll
        for (int i = 0; i < 2; ++i) {
            int p = tid + 256 * i;         // 0..511 = 64 rows x 8 k-octs
            int r = p >> 3, ko = (p & 7) * 8;
            *(short8*)(As + r * 72 + ko) =
                *(const short8*)(A + (size_t)(m0 + r) * 3136 + k0 + ko);
        }
        __syncthreads();
#pragma unroll
        for (int h = 0; h < 2; ++h) {
            short8 af[4];
#pragma unroll
            for (int mt = 0; mt < 4; ++mt)
                af[mt] = *(const short8*)(As + (mt * 16 + n16) * 72 + h * 32 + cig * 8);
            short8 wf[2];
#pragma unroll
            for (int j = 0; j < 2; ++j)
                wf[j] = *(const short8*)(Wb + (size_t)((wv * 2 + j) * 16 + n16) * 3136 +
                                         k0 + h * 32 + cig * 8);
#pragma unroll
            for (int mt = 0; mt < 4; ++mt)
#pragma unroll
                for (int j = 0; j < 2; ++j)
                    acc[mt][j] = __builtin_amdgcn_mfma_f32_16x16x32_bf16(
                        af[mt], wf[j], acc[mt][j], 0, 0, 0);
        }
    }
    float* o = part + (size_t)kh * PB;
#pragma unroll
    for (int mt = 0; mt < 4; ++mt)
#pragma unroll
        for (int j = 0; j < 2; ++j)
#pragma unroll
            for (int r = 0; r < 4; ++r) {
                int row = m0 + mt * 16 + cig * 4 + r;
                o[(size_t)row * 128 + (wv * 2 + j) * 16 + n16] = acc[mt][j][r];
            }
}

// FC2, k-split 4 (R8 version): thread (b,n,q) covers k [32q,32q+32);
// shfl-xor pair reduce. out = relu(sum of 7 partials + fc1b) @ W^T + b2
__global__ __launch_bounds__(256) void fc2_kernel(
    const float* __restrict__ part, size_t PB,
    const float* __restrict__ fc1b,
    const float* __restrict__ W, const float* __restrict__ bias,
    float* __restrict__ out, int total4) {
    __shared__ float smW[10 * 132];
    __shared__ float smB1[128];
    __shared__ float smB[10];
    int t = threadIdx.x;
    for (int i = t; i < 1280; i += 256) {
        int n = i >> 7, k = i & 127;
        smW[n * 132 + k] = W[i];
    }
    if (t < 128) smB1[t] = fc1b[t];
    if (t < 10) smB[t] = bias[t];
    __syncthreads();
    int idx = blockIdx.x * 256 + t;
    if (idx < total4) {
        int j = idx >> 2;         // (b,n)
        int q = idx & 3;          // k-quarter
        int b = j / 10;
        int n = j - b * 10;
        const float* pb = part + (size_t)b * 128 + q * 32;
        const float4* bb = (const float4*)(smB1 + q * 32);
        const float4* wr = (const float4*)(smW + n * 132 + q * 32);
        float acc = 0.f;
#pragma unroll
        for (int c = 0; c < 8; ++c) {
            float4 s = *(const float4*)(pb + 4 * c);
#pragma unroll
            for (int jj = 1; jj < 7; ++jj) {
                float4 pj = *(const float4*)(pb + (size_t)jj * PB + 4 * c);
                s.x += pj.x; s.y += pj.y; s.z += pj.z; s.w += pj.w;
            }
            float4 bv = bb[c];
            float4 w = wr[c];
            acc += fmaxf(s.x + bv.x, 0.f) * w.x + fmaxf(s.y + bv.y, 0.f) * w.y +
                   fmaxf(s.z + bv.z, 0.f) * w.z + fmaxf(s.w + bv.w, 0.f) * w.w;
        }
        acc += __shfl_xor(acc, 1);
        acc += __shfl_xor(acc, 2);
        if (q == 0) out[j] = acc + smB[n];
    }
}

extern "C" void kernel_launch(void* const* d_in, const int* in_sizes, int n_in,
                              void* d_out, int out_size, void* d_ws, size_t ws_size,
                              hipStream_t stream) {
    const float* x    = (const float*)d_in[0];
    const float* w1   = (const float*)d_in[1];
    const float* p1   = (const float*)d_in[2];
    const float* b1   = (const float*)d_in[3];
    const float* w2   = (const float*)d_in[4];
    const float* p2   = (const float*)d_in[5];
    const float* b2   = (const float*)d_in[6];
    const float* fc1w = (const float*)d_in[7];
    const float* fc1b = (const float*)d_in[8];
    const float* fc2w = (const float*)d_in[9];
    const float* fc2b = (const float*)d_in[10];
    float* out = (float*)d_out;

    const int B = in_sizes[0] / 784;  // 4096

    float* ws = (float*)d_ws;
    unsigned short* Kt  = (unsigned short*)ws;             // 51200 sh = 25600 f
    unsigned short* K1b = (unsigned short*)(ws + 25600);   // 2048 sh = 1024 f
    unsigned short* w1b = (unsigned short*)(ws + 26624);   // 401408 sh = 200704 f
    unsigned short* h2b = (unsigned short*)(ws + 227328);  // B*3136 sh = B*1568 f
    float* fc1p = ws + 227328 + (size_t)B * 1568;          // 7*B*128 f

    prep_all<<<404, 256, 0, stream>>>(w1, p1, w2, p2, fc1w, K1b, Kt, w1b);
    fused_conv_mfma<<<B, 256, 0, stream>>>(x, K1b, Kt, b1, b2, h2b);
    fc1_mfma<<<(B / 64) * 7, 256, 0, stream>>>(h2b, w1b, fc1p, (size_t)B * 128);
    fc2_kernel<<<(B * 10 * 4 + 255) / 256, 256, 0, stream>>>(
        fc1p, (size_t)B * 128, fc1b, fc2w, fc2b, out, B * 10 * 4);
}

// Round 10
// 224.919 us; speedup vs baseline: 1.3350x; 1.0823x over previous
//
#include <hip/hip_runtime.h>
#include <hip/hip_bf16.h>

typedef __attribute__((ext_vector_type(8))) short short8;
typedef __attribute__((ext_vector_type(4))) short short4v;
typedef __attribute__((ext_vector_type(4))) float float4v;
typedef __attribute__((ext_vector_type(16))) float float16v;

static __device__ __forceinline__ unsigned short f2bf(float f) {
    unsigned u = __float_as_uint(f);
    unsigned r = (u + 0x7FFF + ((u >> 16) & 1)) >> 16;  // RNE
    return (unsigned short)r;
}

// ---------------------------------------------------------------------------
// ONE prep kernel (R7 version — known good).
//  [0,8)     : K1b[co][k64] bf16 (DCLS gather, conv1 B-operand layout)
//  [8,208)   : Kt[kk][co][ci] bf16 (DCLS gather, conv2 B-operand layout)
//  [208,404) : fc1w fp32 -> w1b bf16 (native (128,3136) layout)
// ---------------------------------------------------------------------------
__global__ __launch_bounds__(256) void prep_all(
    const float* __restrict__ w1, const float* __restrict__ p1,
    const float* __restrict__ w2, const float* __restrict__ p2,
    const float* __restrict__ fc1w,
    unsigned short* __restrict__ K1b,   // (32,64)
    unsigned short* __restrict__ Kt,    // (25,64,32)
    unsigned short* __restrict__ w1b) { // (128,3136)
    const int blk = blockIdx.x;
    const int t = threadIdx.x;

    if (blk < 8) {
        // conv1 weights, B-layout: K1b[co][k], k = wr*8 + kx (zero-padded taps)
        int cell = blk * 256 + t;          // 0..2047
        int co = cell >> 6;
        int k = cell & 63;
        int wr = k >> 3;
        int kx = k & 7;
        float acc = 0.f;
        if (wr < 5 && kx < 5) {
#pragma unroll 8
            for (int kc = 0; kc < 16; ++kc) {
                float wv = w1[co * 16 + kc];
                float pa = p1[co * 16 + kc];
                float pb = p1[512 + co * 16 + kc];
                float pos1 = fminf(fmaxf(pa, -2.f), 2.f) + 2.f;
                float pos2 = fminf(fmaxf(pb, -2.f), 2.f) + 2.f;
                int i1 = (int)floorf(pos1);
                int i2 = (int)floorf(pos2);
                float r1 = pos1 - (float)i1;
                float r2 = pos2 - (float)i2;
                float c = 0.f;
                if (i1 == wr && i2 == kx) c += (1.f - r1) * (1.f - r2);
                if (i1 + 1 == wr && i2 == kx) c += r1 * (1.f - r2);
                if (i1 == wr && i2 + 1 == kx) c += (1.f - r1) * r2;
                if (i1 + 1 == wr && i2 + 1 == kx) c += r1 * r2;
                acc += wv * c;
            }
        }
        K1b[cell] = f2bf(acc);
    } else if (blk < 208) {
        int cell = (blk - 8) * 256 + t;    // 0..51199
        int kk = cell >> 11;
        int co = (cell >> 5) & 63;
        int ci = cell & 31;
        int ky = kk / 5;
        int kx = kk - 5 * ky;
        const int base = (co * 32 + ci) * 32;
        float acc = 0.f;
#pragma unroll 8
        for (int kc = 0; kc < 32; ++kc) {
            float wv = w2[base + kc];
            float pa = p2[base + kc];
            float pb = p2[65536 + base + kc];
            float pos1 = fminf(fmaxf(pa, -2.f), 2.f) + 2.f;
            float pos2 = fminf(fmaxf(pb, -2.f), 2.f) + 2.f;
            int i1 = (int)floorf(pos1);
            int i2 = (int)floorf(pos2);
            float r1 = pos1 - (float)i1;
            float r2 = pos2 - (float)i2;
            float c = 0.f;
            if (i1 == ky && i2 == kx) c += (1.f - r1) * (1.f - r2);
            if (i1 + 1 == ky && i2 == kx) c += r1 * (1.f - r2);
            if (i1 == ky && i2 + 1 == kx) c += (1.f - r1) * r2;
            if (i1 + 1 == ky && i2 + 1 == kx) c += r1 * r2;
            acc += wv * c;
        }
        Kt[cell] = f2bf(acc);
    } else {
        int i8 = ((blk - 208) * 256 + t) * 8;  // < 401408 exactly (196 blocks)
        float4 v0 = *(const float4*)(fc1w + i8);
        float4 v1 = *(const float4*)(fc1w + i8 + 4);
        short8 o = {(short)f2bf(v0.x), (short)f2bf(v0.y), (short)f2bf(v0.z),
                    (short)f2bf(v0.w), (short)f2bf(v1.x), (short)f2bf(v1.y),
                    (short)f2bf(v1.z), (short)f2bf(v1.w)};
        *(short8*)(w1b + i8) = o;
    }
}

// ---------------------------------------------------------------------------
// Fused conv. conv1: 16x16x32 MFMA, 7x7 tiles of 4x4 px (R7-validated).
// conv2: 32x32x16 MFMA — wave owns pooled rows {2wv, 2wv+1}; m = 4*pX + inq
//   so each C/D reg-quad (row = (reg&3)+8(reg>>2)+4(lane>>5)) is one 2x2 pool
//   quad -> pool = 3 in-lane fmax. 8 MFMA/tap/wave (was 16), same ld counts.
// One block (4 waves) per image; LDS 40.5 KB; regs cap 4 blocks/CU.
// ---------------------------------------------------------------------------
__global__ __launch_bounds__(256, 4) void fused_conv_mfma(
    const float* __restrict__ x,             // (B,1,28,28) fp32
    const unsigned short* __restrict__ K1b,  // (32,64)
    const unsigned short* __restrict__ Kt,   // (25,64,32)
    const float* __restrict__ b1,
    const float* __restrict__ b2,
    unsigned short* __restrict__ h2) {       // (B,3136) bf16
    __shared__ __align__(16) unsigned short h1p[18 * 20 * 40];  // [yy][xx][ci(+pad)]
    __shared__ __align__(16) unsigned short sm4[4 * 29 * 44];   // 4 shifted copies; row 28 zero
    __shared__ __align__(16) unsigned short sm_xb[784];

    const int b = blockIdx.x;
    const int tid = threadIdx.x;
    const int lane = tid & 63;
    const int wv = tid >> 6;
    const int n16 = lane & 15;
    const int cig = lane >> 4;

    // conv1 A-side m-mapping (4x4 tile): quad + in-quad
    const int yi = 2 * (n16 >> 3) + ((n16 >> 1) & 1);  // 0..3
    const int xi = 2 * ((n16 >> 2) & 1) + (n16 & 1);   // 0..3
    const int pYo = cig >> 1, pXo = cig & 1;           // conv1 D pooled offsets

    // conv2 lane decode (32x32x16): m = lane&31 -> (pX slot, dy, dx); h = k-group
    const int mq = lane & 31;
    const int Qx = mq >> 2;          // pX slot 0..7
    const int dy2 = (mq >> 1) & 1;
    const int dx2 = mq & 1;
    const int hh = lane >> 5;        // k-group; also output pX parity

    // 1) zero h1p (borders + ci-pads must be 0) + stage image as bf16
    for (int t = tid; t < 1800; t += 256) ((uint4*)h1p)[t] = uint4{0, 0, 0, 0};
    {
        const float* xb = x + (size_t)b * 784;
        for (int t = tid; t < 784; t += 256) sm_xb[t] = f2bf(xb[t]);
    }
    __syncthreads();

    // 2) build 4 shifted copies (copy s pos p = pixel col p+s-4; row 28 = zeros)
    if (tid < 116) {
        int s = tid / 29;
        int r = tid - s * 29;
        unsigned short* dst = sm4 + (s * 29 + r) * 44;
        bool rok = r < 28;
#pragma unroll
        for (int g = 0; g < 11; ++g) {
            short4v v;
#pragma unroll
            for (int e = 0; e < 4; ++e) {
                int c = g * 4 + e + s - 4;
                v[e] = (short)((rok && (unsigned)c < 28u) ? sm_xb[r * 28 + c]
                                                          : (unsigned short)0);
            }
            *(short4v*)(dst + g * 4) = v;
        }
    }

    // conv1 weight B-frags (register-resident) + biases
    short8 bw[2][2];
    float bias1[2], bias2n[2];
#pragma unroll
    for (int cot = 0; cot < 2; ++cot) {
#pragma unroll
        for (int h = 0; h < 2; ++h)
            bw[cot][h] = *(const short8*)(K1b + (cot * 16 + n16) * 64 + h * 32 + cig * 8);
        bias1[cot] = b1[cot * 16 + n16];
    }
#pragma unroll
    for (int nt = 0; nt < 2; ++nt) bias2n[nt] = b2[nt * 32 + mq];

    // per-lane constant part of sm4 address (4tX is always 0 mod 4)
    const int s1 = (xi + 2) & 3;
    const int pb1 = (xi + 2) & ~3;
    const unsigned short* a1base = sm4 + s1 * (29 * 44) + pb1;

    __syncthreads();

    // 3) conv1: 49 tiles (7x7 of 4x4 px), wave-split; 4 MFMA + 2 stores/tile
    for (int i = 0; i < 13; ++i) {
        int t = wv + 4 * i;
        if (t < 49) {
            int tY = t / 7, tX = t - 7 * tY;
            const unsigned short* ab = a1base + 4 * tX;
            int r0 = 4 * tY + yi - 2 + cig;           // window rows 0..3
            int r1 = r0 + 4;                          // window rows 4..7
            int rr0 = ((unsigned)r0 < 28u) ? r0 : 28; // 28 = zero row
            int rr1 = ((unsigned)r1 < 28u) ? r1 : 28;
            short4v lo0 = *(const short4v*)(ab + rr0 * 44);
            short4v hi0 = *(const short4v*)(ab + rr0 * 44 + 4);
            short4v lo1 = *(const short4v*)(ab + rr1 * 44);
            short4v hi1 = *(const short4v*)(ab + rr1 * 44 + 4);
            short8 af0 = {lo0[0], lo0[1], lo0[2], lo0[3], hi0[0], hi0[1], hi0[2], hi0[3]};
            short8 af1 = {lo1[0], lo1[1], lo1[2], lo1[3], hi1[0], hi1[1], hi1[2], hi1[3]};
            int pY = 2 * tY + pYo, pX = 2 * tX + pXo;
#pragma unroll
            for (int cot = 0; cot < 2; ++cot) {
                float4v acc = {0.f, 0.f, 0.f, 0.f};
                acc = __builtin_amdgcn_mfma_f32_16x16x32_bf16(af0, bw[cot][0], acc, 0, 0, 0);
                acc = __builtin_amdgcn_mfma_f32_16x16x32_bf16(af1, bw[cot][1], acc, 0, 0, 0);
                float v = fmaxf(fmaxf(acc[0], acc[1]), fmaxf(acc[2], acc[3]));
                v = fmaxf(v + bias1[cot], 0.f);
                h1p[((pY + 2) * 20 + (pX + 2)) * 40 + cot * 16 + n16] = f2bf(v);
            }
        }
    }
    __syncthreads();

    // 4) conv2: 32x32x16. Wave -> pooled rows pY = 2wv+mt; A lane m -> (Qx,dy,dx);
    //    k = ci = khalf*16 + hh*8 + j. Phantom x/y clamped, discarded at write.
    int x2 = 2 * Qx + dx2;
    if (x2 > 13) x2 = 13;
    int aoff[2][2];
    int pYv[2];
#pragma unroll
    for (int mt = 0; mt < 2; ++mt) {
        int pY = 2 * wv + mt;            // 0..7
        int y2 = 2 * pY + dy2;           // 0..15
        if (y2 > 13) y2 = 13;
        pYv[mt] = pY;
#pragma unroll
        for (int kh2 = 0; kh2 < 2; ++kh2)
            aoff[mt][kh2] = (y2 * 20 + x2) * 40 + kh2 * 16 + hh * 8;
    }

    float16v acc2[2][2];  // [mt][nt] = 64 AGPR
#pragma unroll
    for (int mt = 0; mt < 2; ++mt)
#pragma unroll
        for (int nt = 0; nt < 2; ++nt)
#pragma unroll
            for (int e = 0; e < 16; ++e) acc2[mt][nt][e] = 0.f;

#pragma unroll
    for (int ky = 0; ky < 5; ++ky) {
#pragma unroll
        for (int kx = 0; kx < 5; ++kx) {
            int kk = ky * 5 + kx;
            short8 wf[2][2];  // [nt][khalf]
#pragma unroll
            for (int nt = 0; nt < 2; ++nt)
#pragma unroll
                for (int kh2 = 0; kh2 < 2; ++kh2)
                    wf[nt][kh2] = *(const short8*)(Kt + kk * 2048 +
                        (nt * 32 + mq) * 32 + kh2 * 16 + hh * 8);
#pragma unroll
            for (int mt = 0; mt < 2; ++mt) {
                short8 af0 = *(const short8*)(h1p + aoff[mt][0] + (ky * 20 + kx) * 40);
                short8 af1 = *(const short8*)(h1p + aoff[mt][1] + (ky * 20 + kx) * 40);
#pragma unroll
                for (int nt = 0; nt < 2; ++nt) {
                    acc2[mt][nt] = __builtin_amdgcn_mfma_f32_32x32x16_bf16(
                        af0, wf[nt][0], acc2[mt][nt], 0, 0, 0);
                    acc2[mt][nt] = __builtin_amdgcn_mfma_f32_32x32x16_bf16(
                        af1, wf[nt][1], acc2[mt][nt], 0, 0, 0);
                }
            }
        }
    }

    // epilogue: reg-quad g holds rows 8g+4hh+{0..3} = pool quad pX = 2g+hh
    unsigned short* outb = h2 + (size_t)b * 3136;
#pragma unroll
    for (int mt = 0; mt < 2; ++mt) {
        if (pYv[mt] < 7) {
#pragma unroll
            for (int nt = 0; nt < 2; ++nt) {
#pragma unroll
                for (int g = 0; g < 4; ++g) {
                    int pX = 2 * g + hh;
                    float v = fmaxf(fmaxf(acc2[mt][nt][4 * g], acc2[mt][nt][4 * g + 1]),
                                    fmaxf(acc2[mt][nt][4 * g + 2], acc2[mt][nt][4 * g + 3]));
                    v = fmaxf(v + bias2n[nt], 0.f);
                    if (pX < 7)
                        outb[(nt * 32 + mq) * 49 + pYv[mt] * 7 + pX] = f2bf(v);
                }
            }
        }
    }
}

// ---------------------------------------------------------------------------
// FC1 MFMA, 64-row blocks (R8/R9 version): partials[kh](B,128) = A @ W^T slice
// kh (K-split 7). A-tile staged in LDS; waves split N. Plain stores.
__global__ __launch_bounds__(256) void fc1_mfma(
    const unsigned short* __restrict__ A,
    const unsigned short* __restrict__ Wb,
    float* __restrict__ part, size_t PB) {  // PB = B*128
    __shared__ __align__(16) unsigned short As[64 * 72];  // stride 72 breaks banks
    const int blk = blockIdx.x;
    const int kh = blk % 7;
    const int m0 = (blk / 7) * 64;
    const int tid = threadIdx.x;
    const int wv = tid >> 6;
    const int lane = tid & 63;
    const int n16 = lane & 15;
    const int cig = lane >> 4;

    float4v acc[4][2];  // [mt][j]
#pragma unroll
    for (int mt = 0; mt < 4; ++mt)
#pragma unroll
        for (int j = 0; j < 2; ++j) acc[mt][j] = float4v{0.f, 0.f, 0.f, 0.f};

    for (int it = 0; it < 7; ++it) {
        int k0 = kh * 448 + it * 64;
        __syncthreads();
#pragma unroll
        for (int i = 0; i < 2; ++i) {
            int p = tid + 256 * i;         // 0..511 = 64 rows x 8 k-octs
            int r = p >> 3, ko = (p & 7) * 8;
            *(short8*)(As + r * 72 + ko) =
                *(const short8*)(A + (size_t)(m0 + r) * 3136 + k0 + ko);
        }
        __syncthreads();
#pragma unroll
        for (int h = 0; h < 2; ++h) {
            short8 af[4];
#pragma unroll
            for (int mt = 0; mt < 4; ++mt)
                af[mt] = *(const short8*)(As + (mt * 16 + n16) * 72 + h * 32 + cig * 8);
            short8 wf[2];
#pragma unroll
            for (int j = 0; j < 2; ++j)
                wf[j] = *(const short8*)(Wb + (size_t)((wv * 2 + j) * 16 + n16) * 3136 +
                                         k0 + h * 32 + cig * 8);
#pragma unroll
            for (int mt = 0; mt < 4; ++mt)
#pragma unroll
                for (int j = 0; j < 2; ++j)
                    acc[mt][j] = __builtin_amdgcn_mfma_f32_16x16x32_bf16(
                        af[mt], wf[j], acc[mt][j], 0, 0, 0);
        }
    }
    float* o = part + (size_t)kh * PB;
#pragma unroll
    for (int mt = 0; mt < 4; ++mt)
#pragma unroll
        for (int j = 0; j < 2; ++j)
#pragma unroll
            for (int r = 0; r < 4; ++r) {
                int row = m0 + mt * 16 + cig * 4 + r;
                o[(size_t)row * 128 + (wv * 2 + j) * 16 + n16] = acc[mt][j][r];
            }
}

// FC2 row-centric: thread (r,q) builds relu(sum of 7 partials + b1) for its
// 16-k slice ONCE (part read 1x, not 10x), dots vs all 10 W rows from LDS,
// shfl-xor(1,2,4) k-reduce. Block = 32 rows; grid B/32.
__global__ __launch_bounds__(256) void fc2_kernel(
    const float* __restrict__ part, size_t PB,
    const float* __restrict__ fc1b,
    const float* __restrict__ W, const float* __restrict__ bias,
    float* __restrict__ out) {
    __shared__ float smW[10 * 132];
    __shared__ float smB1[128];
    __shared__ float smB[10];
    int t = threadIdx.x;
    for (int i = t; i < 1280; i += 256) {
        int n = i >> 7, k = i & 127;
        smW[n * 132 + k] = W[i];
    }
    if (t < 128) smB1[t] = fc1b[t];
    if (t < 10) smB[t] = bias[t];
    __syncthreads();
    const int r = t >> 3;          // 0..31 (batch row in block)
    const int q = t & 7;           // 16-float k-slice
    const size_t b = (size_t)blockIdx.x * 32 + r;
    const float* pb = part + b * 128 + q * 16;

    float rv[16];
#pragma unroll
    for (int c = 0; c < 4; ++c) {
        float4 s = *(const float4*)(pb + 4 * c);
#pragma unroll
        for (int j = 1; j < 7; ++j) {
            float4 pj = *(const float4*)(pb + (size_t)j * PB + 4 * c);
            s.x += pj.x; s.y += pj.y; s.z += pj.z; s.w += pj.w;
        }
        float4 bv = *(const float4*)(smB1 + q * 16 + 4 * c);
        rv[4 * c + 0] = fmaxf(s.x + bv.x, 0.f);
        rv[4 * c + 1] = fmaxf(s.y + bv.y, 0.f);
        rv[4 * c + 2] = fmaxf(s.z + bv.z, 0.f);
        rv[4 * c + 3] = fmaxf(s.w + bv.w, 0.f);
    }
    float acc[10];
#pragma unroll
    for (int n = 0; n < 10; ++n) {
        const float4* wr = (const float4*)(smW + n * 132 + q * 16);
        float a = 0.f;
#pragma unroll
        for (int c = 0; c < 4; ++c) {
            float4 w = wr[c];
            a += rv[4 * c] * w.x + rv[4 * c + 1] * w.y +
                 rv[4 * c + 2] * w.z + rv[4 * c + 3] * w.w;
        }
        acc[n] = a;
    }
#pragma unroll
    for (int n = 0; n < 10; ++n) {
        acc[n] += __shfl_xor(acc[n], 1);
        acc[n] += __shfl_xor(acc[n], 2);
        acc[n] += __shfl_xor(acc[n], 4);
    }
    if (q == 0) {
#pragma unroll
        for (int n = 0; n < 10; ++n) out[b * 10 + n] = acc[n] + smB[n];
    }
}

extern "C" void kernel_launch(void* const* d_in, const int* in_sizes, int n_in,
                              void* d_out, int out_size, void* d_ws, size_t ws_size,
                              hipStream_t stream) {
    const float* x    = (const float*)d_in[0];
    const float* w1   = (const float*)d_in[1];
    const float* p1   = (const float*)d_in[2];
    const float* b1   = (const float*)d_in[3];
    const float* w2   = (const float*)d_in[4];
    const float* p2   = (const float*)d_in[5];
    const float* b2   = (const float*)d_in[6];
    const float* fc1w = (const float*)d_in[7];
    const float* fc1b = (const float*)d_in[8];
    const float* fc2w = (const float*)d_in[9];
    const float* fc2b = (const float*)d_in[10];
    float* out = (float*)d_out;

    const int B = in_sizes[0] / 784;  // 4096

    float* ws = (float*)d_ws;
    unsigned short* Kt  = (unsigned short*)ws;             // 51200 sh = 25600 f
    unsigned short* K1b = (unsigned short*)(ws + 25600);   // 2048 sh = 1024 f
    unsigned short* w1b = (unsigned short*)(ws + 26624);   // 401408 sh = 200704 f
    unsigned short* h2b = (unsigned short*)(ws + 227328);  // B*3136 sh = B*1568 f
    float* fc1p = ws + 227328 + (size_t)B * 1568;          // 7*B*128 f

    prep_all<<<404, 256, 0, stream>>>(w1, p1, w2, p2, fc1w, K1b, Kt, w1b);
    fused_conv_mfma<<<B, 256, 0, stream>>>(x, K1b, Kt, b1, b2, h2b);
    fc1_mfma<<<(B / 64) * 7, 256, 0, stream>>>(h2b, w1b, fc1p, (size_t)B * 128);
    fc2_kernel<<<B / 32, 256, 0, stream>>>(fc1p, (size_t)B * 128,
                                           fc1b, fc2w, fc2b, out);
}